// Round 8
// baseline (390.784 us; speedup 1.0000x reference)
//
#include <hip/hip_runtime.h>

#define RPB  32     // rows per block
#define NTHR 128    // 2 waves: ch = wid (0..1); each wave 32 rows x 64 cols

typedef _Float16 f16;
typedef _Float16 f16x2 __attribute__((ext_vector_type(2)));
typedef _Float16 f16x4 __attribute__((ext_vector_type(4)));
typedef _Float16 f16x8 __attribute__((ext_vector_type(8)));
typedef float    f32x4 __attribute__((ext_vector_type(4)));

// ---- workspace layout: weights packed to f16 in B-fragment order ----
#define G_MW2 1024                 // 128*64/8
#define G_W   2048                 // 128*128/8
#define G_MW3 16384                // 1024*128/8
#define GO_MW2 0
#define GO_W2  (GO_MW2 + G_MW2)
#define GO_W3  (GO_W2 + G_W)
#define GO_W4  (GO_W3 + G_W)
#define GO_MW3 (GO_W4 + G_W)
#define G_TOT  (GO_MW3 + G_MW3)    // 23552 groups
#define WS_BYTES ((size_t)G_TOT * 16)

// ---- LDS layout (bytes), per 32-row block ----
#define OFF_H2    0
#define OFF_B     8704
#define OFF_META  (OFF_B)
#define OFF_H1    (OFF_B + 2048)
#define OFF_STATS (OFF_B + 8704)       // 17408
#define OFF_OUT   (OFF_STATS + 512)    // 17920
#define OFF_X     (OFF_OUT + 256)      // 18176
#define SMEM_SZ   (OFF_X + 128)        // 18304

__device__ __forceinline__ f16x8 cvt8(const float* __restrict__ p) {
  const float4* p4 = (const float4*)p;
  float4 f0 = p4[0], f1 = p4[1];
  f16x8 o;
  o[0]=(f16)f0.x; o[1]=(f16)f0.y; o[2]=(f16)f0.z; o[3]=(f16)f0.w;
  o[4]=(f16)f1.x; o[5]=(f16)f1.y; o[6]=(f16)f1.z; o[7]=(f16)f1.w;
  return o;
}

__global__ void pack_weights(const float* __restrict__ mw2, const float* __restrict__ w2,
                             const float* __restrict__ w3,  const float* __restrict__ w4,
                             const float* __restrict__ mw3, f16x8* __restrict__ ws) {
  int g = blockIdx.x * blockDim.x + threadIdx.x;
  if (g >= G_TOT) return;
  if (g < GO_MW3) {                 // linear-packed matrices
    const float* W; int K; int local;
    if (g < GO_W2)       { W = mw2; K = 64;  local = g; }
    else if (g < GO_W3)  { W = w2;  K = 128; local = g - GO_W2; }
    else if (g < GO_W4)  { W = w3;  K = 128; local = g - GO_W3; }
    else                 { W = w4;  K = 128; local = g - GO_W4; }
    const int lane = local & 63, fb = local >> 6;
    const int ksteps = K >> 5;
    const int ks = fb % ksteps, n0g = fb / ksteps;
    const int n  = n0g * 16 + (lane & 15);
    const int k0 = ks * 32 + (lane >> 4) * 8;
    ws[g] = cvt8(W + (size_t)n * K + k0);
  } else {                          // mw3: AdaIN-interleaved
    const int local = g - GO_MW3;
    const int lane = local & 63, fb = local >> 6;   // fb: l(2) ch(1) tt(2) sb(1) ks(2)
    const int ks = fb & 3, sb = (fb >> 2) & 1, tt = (fb >> 3) & 3;
    const int ch = (fb >> 5) & 1, l = fb >> 6;
    const int n  = l * 256 + 2 * (ch * 64 + tt * 16 + (lane & 15)) + sb;
    const int k0 = ks * 32 + (lane >> 4) * 8;
    ws[g] = cvt8(mw3 + (size_t)n * 128 + k0);
  }
}

template<bool WS>
__device__ __forceinline__ f16x8 ldB(const f16x8* __restrict__ wp,
                                     const float* __restrict__ wf,
                                     int K, int n0, int ks, int lane) {
  if constexpr (WS) {
    return wp[((n0 >> 4) * (K >> 5) + ks) * 64 + lane];
  } else {
    const int n  = n0 + (lane & 15);
    const int k0 = ks * 32 + (lane >> 4) * 8;
    return cvt8(wf + (size_t)n * K + k0);
  }
}

template<bool WS>
__device__ __forceinline__ f16x8 ldB3(const f16x8* __restrict__ wp,
                                      const float* __restrict__ wf,
                                      int l, int ch, int tt, int sb, int ks, int lane) {
  if constexpr (WS) {
    const int fb = (((l * 2 + ch) * 4 + tt) * 2 + sb) * 4 + ks;
    return wp[fb * 64 + lane];
  } else {
    const int n  = l * 256 + 2 * (ch * 64 + tt * 16 + (lane & 15)) + sb;
    const int k0 = ks * 32 + (lane >> 4) * 8;
    return cvt8(wf + (size_t)n * 128 + k0);
  }
}

#define MFMA(a, b, c) __builtin_amdgcn_mfma_f32_16x16x32_f16((a), (b), (c), 0, 0, 0)

// ---- prefetch group macros (named buffers, literal TT -> static reg indices) ----
#define STY_G(B, L, TT) do {                                            \
  _Pragma("unroll") for (int sb_ = 0; sb_ < 2; ++sb_)                   \
  _Pragma("unroll") for (int ks_ = 0; ks_ < 4; ++ks_)                   \
    B[sb_][ks_] = ldB3<WS>(wsp3, mw3, (L), ch, (TT), sb_, ks_, lane);   \
} while (0)

#define STY_C(B, TT) do {                                               \
  f32x4 a00={0,0,0,0}, a01={0,0,0,0}, a10={0,0,0,0}, a11={0,0,0,0};     \
  _Pragma("unroll") for (int ks_ = 0; ks_ < 4; ++ks_) {                 \
    a00 = MFMA(aH[0][ks_], B[0][ks_], a00);                             \
    a01 = MFMA(aH[1][ks_], B[0][ks_], a01);                             \
    a10 = MFMA(aH[0][ks_], B[1][ks_], a10);                             \
    a11 = MFMA(aH[1][ks_], B[1][ks_], a11);                             \
  }                                                                     \
  _Pragma("unroll") for (int q_ = 0; q_ < 4; ++q_) {                    \
    scv[0][TT][q_] = (f16)(a00[q_] + mbt[TT].x);                        \
    scv[1][TT][q_] = (f16)(a01[q_] + mbt[TT].x);                        \
    biv[0][TT][q_] = (f16)(a10[q_] + mbt[TT].y);                        \
    biv[1][TT][q_] = (f16)(a11[q_] + mbt[TT].y);                        \
  }                                                                     \
} while (0)

#define MAIN_G(B, TT) do {                                              \
  _Pragma("unroll") for (int ks_ = 0; ks_ < 4; ++ks_)                   \
    B[ks_] = ldB<WS>(Wp_, Wf_, 128, ch * 64 + (TT) * 16, ks_, lane);    \
  bvv[TT] = Bv_[ch * 64 + (TT) * 16 + ln];                              \
} while (0)

#define MAIN_C(B, TT) do {                                              \
  f32x4 m0={0,0,0,0}, m1={0,0,0,0};                                     \
  _Pragma("unroll") for (int ks_ = 0; ks_ < 4; ++ks_) {                 \
    m0 = MFMA(aY[0][ks_], B[ks_], m0);                                  \
    m1 = MFMA(aY[1][ks_], B[ks_], m1);                                  \
  }                                                                     \
  _Pragma("unroll") for (int q_ = 0; q_ < 4; ++q_) {                    \
    accM[0][TT][q_] = m0[q_] + bvv[TT];                                 \
    accM[1][TT][q_] = m1[q_] + bvv[TT];                                 \
  }                                                                     \
} while (0)

template<bool WS>
__global__ __launch_bounds__(NTHR, 2)   // min 2 waves/EU -> reg cap 256 (no spill, no 1-wave band)
void adain_mfma(const float* __restrict__ x,   const float* __restrict__ meta,
                const float* __restrict__ mw1, const float* __restrict__ mb1,
                const float* __restrict__ mw2, const float* __restrict__ mb2,
                const float* __restrict__ mw3, const float* __restrict__ mb3,
                const float* __restrict__ w1,  const float* __restrict__ b1,
                const float* __restrict__ w2,  const float* __restrict__ b2,
                const float* __restrict__ w3,  const float* __restrict__ b3,
                const float* __restrict__ w4,  const float* __restrict__ b4,
                const float* __restrict__ w5,  const float* __restrict__ b5,
                const f16x8* __restrict__ wsp, float* __restrict__ out)
{
  __shared__ __align__(16) char smem[SMEM_SZ];
  f16    (*sH2)[136]   = (f16(*)[136])  (smem + OFF_H2);
  float  (*sMeta)[16]  = (float(*)[16]) (smem + OFF_META);
  f16    (*sH1)[72]    = (f16(*)[72])   (smem + OFF_H1);
  f16    (*sY)[136]    = (f16(*)[136])  (smem + OFF_B);
  float2 (*sStats)[2]  = (float2(*)[2]) (smem + OFF_STATS);
  float  (*sOut)[2]    = (float(*)[2])  (smem + OFF_OUT);
  float  *sX           = (float*)       (smem + OFF_X);

  const int t    = threadIdx.x;
  const int lane = t & 63;
  const int ch   = t >> 6;            // wave id == column half
  const int r0   = blockIdx.x * RPB;
  const int ln   = lane & 15;         // fragment n / A-row index
  const int bg   = lane >> 4;         // k-subgroup
  const int acol = bg * 8;
  const int g4   = bg * 4;            // D-row base offset

  const f16x8* wsp3 = wsp + GO_MW3;

  // ---- stage metadata + x ----
  ((float4*)&sMeta[0][0])[t] = ((const float4*)(meta + (size_t)r0 * 16))[t];
  if (t < RPB) sX[t] = x[r0 + t];

  // ---- EARLY PREFETCH: h2 B-frags + mb2 + style(l=0) groups 0,1 ----
  // (no data deps; lands during h1 compute ~600 cyc)
  f16x8 bh[4][2];
  float bb2[4];
#pragma unroll
  for (int tt = 0; tt < 4; ++tt) {
    bh[tt][0] = ldB<WS>(wsp + GO_MW2, mw2, 64, ch * 64 + tt * 16, 0, lane);
    bh[tt][1] = ldB<WS>(wsp + GO_MW2, mw2, 64, ch * 64 + tt * 16, 1, lane);
    bb2[tt]   = mb2[ch * 64 + tt * 16 + ln];
  }
  f16x8 bsA[2][4], bsB[2][4];
  STY_G(bsA, 0, 0);
  STY_G(bsB, 0, 1);

  // ---- h1 = relu(meta @ mw1.T + mb1) : (32,16)->(32,64), VALU ----
  {
    const int j = t & 63, rg = t >> 6;
    float wr[16];
    const float4* p4 = (const float4*)(mw1 + j * 16);
#pragma unroll
    for (int q = 0; q < 4; ++q) {
      float4 f = p4[q];
      wr[4*q] = f.x; wr[4*q+1] = f.y; wr[4*q+2] = f.z; wr[4*q+3] = f.w;
    }
    const float bj = mb1[j];
#pragma unroll
    for (int rr = 0; rr < 16; ++rr) {
      const int r = rg * 16 + rr;
      float acc = bj;
#pragma unroll
      for (int k = 0; k < 16; ++k) acc += wr[k] * sMeta[r][k];
      sH1[r][j] = (f16)fmaxf(acc, 0.0f);
    }
  }
  __syncthreads();

  // ---- h2 = relu(h1 @ mw2.T + mb2) : MFMA K=64 (frags prefetched) ----
  {
    f16x8 a0[2], a1[2];
#pragma unroll
    for (int p = 0; p < 2; ++p) {
      const int ar = p * 16 + ln;
      a0[p] = *(const f16x8*)&sH1[ar][acol];
      a1[p] = *(const f16x8*)&sH1[ar][32 + acol];
    }
#pragma unroll
    for (int tt = 0; tt < 4; ++tt) {
      const int n0 = ch * 64 + tt * 16;
#pragma unroll
      for (int p = 0; p < 2; ++p) {
        f32x4 acc = {0.f, 0.f, 0.f, 0.f};
        acc = MFMA(a0[p], bh[tt][0], acc);
        acc = MFMA(a1[p], bh[tt][1], acc);
        const int dr = p * 16 + g4;
#pragma unroll
        for (int q = 0; q < 4; ++q)
          sH2[dr + q][n0 + ln] = (f16)fmaxf(acc[q] + bb2[tt], 0.0f);
      }
    }
  }
  __syncthreads();

  // ---- A-frags of h2: loaded once, live across all 4 layers ----
  f16x8 aH[2][4];
#pragma unroll
  for (int p = 0; p < 2; ++p) {
    const int ar = p * 16 + ln;
#pragma unroll
    for (int ks = 0; ks < 4; ++ks)
      aH[p][ks] = *(const f16x8*)&sH2[ar][ks * 32 + acol];
  }

  // ---- 4 AdaIN layers ----
#pragma unroll 1
  for (int l = 0; l < 4; ++l) {
    const f16x8* Wp_ = (l == 1) ? wsp + GO_W2 : (l == 2) ? wsp + GO_W3 : wsp + GO_W4;
    const float* Wf_ = (l == 1) ? w2 : (l == 2) ? w3 : w4;
    const float* Bv_ = (l == 1) ? b2 : (l == 2) ? b3 : b4;

    float2 mbt[4];
#pragma unroll
    for (int tt = 0; tt < 4; ++tt)
      mbt[tt] = *(const float2*)(mb3 + l * 256 + 2 * (ch * 64 + tt * 16 + ln));

    // (a) style: compute g (prefetched), refill g+2; issue main g0/g1 in tail
    f16x4 scv[2][4], biv[2][4];
    f16x8 bmA[4], bmB[4];
    float bvv[4];
    STY_C(bsA, 0);  STY_G(bsA, l, 2);
    STY_C(bsB, 1);  STY_G(bsB, l, 3);
    STY_C(bsA, 2);  if (l) MAIN_G(bmA, 0);
    STY_C(bsB, 3);  if (l) MAIN_G(bmB, 1);

    // (b) main-chain pre-activation
    f32x4 accM[2][4];
    if (l == 0) {
#pragma unroll
      for (int tt = 0; tt < 4; ++tt) {
        const int c = ch * 64 + tt * 16 + ln;
        const float w1c = w1[c], b1c = b1[c];
#pragma unroll
        for (int p = 0; p < 2; ++p) {
          const int dr = p * 16 + g4;
#pragma unroll
          for (int q = 0; q < 4; ++q) accM[p][tt][q] = sX[dr + q] * w1c + b1c;
        }
      }
    } else {
      f16x8 aY[2][4];
#pragma unroll
      for (int p = 0; p < 2; ++p) {
        const int ar = p * 16 + ln;
#pragma unroll
        for (int ks = 0; ks < 4; ++ks)
          aY[p][ks] = *(const f16x8*)&sY[ar][ks * 32 + acol];
      }
      MAIN_C(bmA, 0);  MAIN_G(bmA, 2);
      MAIN_C(bmB, 1);  MAIN_G(bmB, 3);
      MAIN_C(bmA, 2);
      MAIN_C(bmB, 3);
    }

    // prefetch next layer's style g0/g1 (lands under stats+apply VALU)
    if (l < 3) {
      STY_G(bsA, l + 1, 0);
      STY_G(bsB, l + 1, 1);
    }

    // (c) row stats: shuffle-reduce within 16-lane groups, cross-ch via LDS
#pragma unroll
    for (int p = 0; p < 2; ++p) {
      float s1[4] = {0,0,0,0}, s2[4] = {0,0,0,0};
#pragma unroll
      for (int tt = 0; tt < 4; ++tt)
#pragma unroll
        for (int q = 0; q < 4; ++q) {
          const float v = accM[p][tt][q];
          s1[q] += v; s2[q] += v * v;
        }
#pragma unroll
      for (int m = 1; m < 16; m <<= 1)
#pragma unroll
        for (int q = 0; q < 4; ++q) {
          s1[q] += __shfl_xor(s1[q], m, 64);
          s2[q] += __shfl_xor(s2[q], m, 64);
        }
      if (ln == 0) {
        const int dr = p * 16 + g4;
#pragma unroll
        for (int q = 0; q < 4; ++q) sStats[dr + q][ch] = make_float2(s1[q], s2[q]);
      }
    }
    __syncthreads();

    float mu[2][4], rsg[2][4];
#pragma unroll
    for (int p = 0; p < 2; ++p) {
      const int dr = p * 16 + g4;
#pragma unroll
      for (int q = 0; q < 4; ++q) {
        const float2 A = sStats[dr + q][0], Bc = sStats[dr + q][1];
        const float S1 = A.x + Bc.x, S2 = A.y + Bc.y;
        const float m = S1 * (1.0f / 128.0f);
        float var = (S2 - S1 * m) * (1.0f / 127.0f);
        var = fmaxf(var, 0.0f);
        mu[p][q]  = m;
        rsg[p][q] = 1.0f / (sqrtf(var) + 1e-6f);
      }
    }

    // (d) apply adain + lrelu; store sY (layers 0-2) or fuse w5 dot (layer 3)
    if (l < 3) {
#pragma unroll
      for (int tt = 0; tt < 4; ++tt) {
        const int c = ch * 64 + tt * 16 + ln;
#pragma unroll
        for (int p = 0; p < 2; ++p) {
          const int dr = p * 16 + g4;
#pragma unroll
          for (int q = 0; q < 4; ++q) {
            float v = (float)scv[p][tt][q] * (accM[p][tt][q] - mu[p][q]) * rsg[p][q]
                      + (float)biv[p][tt][q];
            v = fmaxf(v, 0.01f * v);
            sY[dr + q][c] = (f16)v;
          }
        }
      }
      __syncthreads();
    } else {
      float o[2][4] = {{0,0,0,0},{0,0,0,0}};
#pragma unroll
      for (int tt = 0; tt < 4; ++tt) {
        const int c = ch * 64 + tt * 16 + ln;
        const float w5c = w5[c];
#pragma unroll
        for (int p = 0; p < 2; ++p)
#pragma unroll
          for (int q = 0; q < 4; ++q) {
            float v = (float)scv[p][tt][q] * (accM[p][tt][q] - mu[p][q]) * rsg[p][q]
                      + (float)biv[p][tt][q];
            v = fmaxf(v, 0.01f * v);
            o[p][q] += v * w5c;
          }
      }
#pragma unroll
      for (int m = 1; m < 16; m <<= 1)
#pragma unroll
        for (int p = 0; p < 2; ++p)
#pragma unroll
          for (int q = 0; q < 4; ++q) o[p][q] += __shfl_xor(o[p][q], m, 64);
      if (ln == 0) {
#pragma unroll
        for (int p = 0; p < 2; ++p) {
          const int dr = p * 16 + g4;
#pragma unroll
          for (int q = 0; q < 4; ++q) sOut[dr + q][ch] = o[p][q];
        }
      }
      __syncthreads();
      if (t < RPB) {
        float v = sOut[t][0] + sOut[t][1] + b5[0];
        v = fmaxf(v, 0.01f * v);
        out[r0 + t] = v;
      }
    }
  }
}

extern "C" void kernel_launch(void* const* d_in, const int* in_sizes, int n_in,
                              void* d_out, int out_size, void* d_ws, size_t ws_size,
                              hipStream_t stream) {
  const float* x    = (const float*)d_in[0];
  const float* meta = (const float*)d_in[1];
  const float* mw1  = (const float*)d_in[2];
  const float* mb1  = (const float*)d_in[3];
  const float* mw2  = (const float*)d_in[4];
  const float* mb2  = (const float*)d_in[5];
  const float* mw3  = (const float*)d_in[6];
  const float* mb3  = (const float*)d_in[7];
  const float* w1   = (const float*)d_in[8];
  const float* b1   = (const float*)d_in[9];
  const float* w2   = (const float*)d_in[10];
  const float* b2   = (const float*)d_in[11];
  const float* w3   = (const float*)d_in[12];
  const float* b3   = (const float*)d_in[13];
  const float* w4   = (const float*)d_in[14];
  const float* b4   = (const float*)d_in[15];
  const float* w5   = (const float*)d_in[16];
  const float* b5   = (const float*)d_in[17];
  float* out = (float*)d_out;

  const int nrows = in_sizes[0];        // 262144
  const int grid  = nrows / RPB;        // 8192

  const bool usews = (ws_size >= WS_BYTES) && (d_ws != nullptr);
  if (usews) {
    f16x8* wsp = (f16x8*)d_ws;
    hipLaunchKernelGGL(pack_weights, dim3((G_TOT + 255) / 256), dim3(256), 0, stream,
                       mw2, w2, w3, w4, mw3, wsp);
    hipLaunchKernelGGL(adain_mfma<true>, dim3(grid), dim3(NTHR), 0, stream,
                       x, meta, mw1, mb1, mw2, mb2, mw3, mb3,
                       w1, b1, w2, b2, w3, b3, w4, b4, w5, b5, wsp, out);
  } else {
    hipLaunchKernelGGL(adain_mfma<false>, dim3(grid), dim3(NTHR), 0, stream,
                       x, meta, mw1, mb1, mw2, mb2, mw3, mb3,
                       w1, b1, w2, b2, w3, b3, w4, b4, w5, b5, (const f16x8*)nullptr, out);
  }
}

// Round 10
// 285.778 us; speedup vs baseline: 1.3674x; 1.3674x over previous
//
#include <hip/hip_runtime.h>

#define RPB  32     // rows per block
#define NTHR 128    // 2 waves: ch = wid (0..1); each wave 32 rows x 64 cols

typedef _Float16 f16;
typedef _Float16 f16x2 __attribute__((ext_vector_type(2)));
typedef _Float16 f16x4 __attribute__((ext_vector_type(4)));
typedef _Float16 f16x8 __attribute__((ext_vector_type(8)));
typedef float    f32x4 __attribute__((ext_vector_type(4)));

// ---- workspace layout: weights packed to f16 in B-fragment order ----
#define G_MW2 1024                 // 128*64/8
#define G_W   2048                 // 128*128/8
#define G_MW3 16384                // 1024*128/8
#define GO_MW2 0
#define GO_W2  (GO_MW2 + G_MW2)
#define GO_W3  (GO_W2 + G_W)
#define GO_W4  (GO_W3 + G_W)
#define GO_MW3 (GO_W4 + G_W)
#define G_TOT  (GO_MW3 + G_MW3)    // 23552 groups
#define WS_BYTES ((size_t)G_TOT * 16)

// ---- LDS layout (bytes), per 32-row block ----
#define OFF_H2    0
#define OFF_B     8704
#define OFF_META  (OFF_B)
#define OFF_H1    (OFF_B + 2048)
#define OFF_STATS (OFF_B + 8704)       // 17408
#define OFF_OUT   (OFF_STATS + 512)    // 17920
#define OFF_X     (OFF_OUT + 256)      // 18176
#define SMEM_SZ   (OFF_X + 128)        // 18304

__device__ __forceinline__ f16x8 cvt8(const float* __restrict__ p) {
  const float4* p4 = (const float4*)p;
  float4 f0 = p4[0], f1 = p4[1];
  f16x8 o;
  o[0]=(f16)f0.x; o[1]=(f16)f0.y; o[2]=(f16)f0.z; o[3]=(f16)f0.w;
  o[4]=(f16)f1.x; o[5]=(f16)f1.y; o[6]=(f16)f1.z; o[7]=(f16)f1.w;
  return o;
}

__global__ void pack_weights(const float* __restrict__ mw2, const float* __restrict__ w2,
                             const float* __restrict__ w3,  const float* __restrict__ w4,
                             const float* __restrict__ mw3, f16x8* __restrict__ ws) {
  int g = blockIdx.x * blockDim.x + threadIdx.x;
  if (g >= G_TOT) return;
  if (g < GO_MW3) {                 // linear-packed matrices
    const float* W; int K; int local;
    if (g < GO_W2)       { W = mw2; K = 64;  local = g; }
    else if (g < GO_W3)  { W = w2;  K = 128; local = g - GO_W2; }
    else if (g < GO_W4)  { W = w3;  K = 128; local = g - GO_W3; }
    else                 { W = w4;  K = 128; local = g - GO_W4; }
    const int lane = local & 63, fb = local >> 6;
    const int ksteps = K >> 5;
    const int ks = fb % ksteps, n0g = fb / ksteps;
    const int n  = n0g * 16 + (lane & 15);
    const int k0 = ks * 32 + (lane >> 4) * 8;
    ws[g] = cvt8(W + (size_t)n * K + k0);
  } else {                          // mw3: AdaIN-interleaved
    const int local = g - GO_MW3;
    const int lane = local & 63, fb = local >> 6;   // fb: l(2) ch(1) tt(2) sb(1) ks(2)
    const int ks = fb & 3, sb = (fb >> 2) & 1, tt = (fb >> 3) & 3;
    const int ch = (fb >> 5) & 1, l = fb >> 6;
    const int n  = l * 256 + 2 * (ch * 64 + tt * 16 + (lane & 15)) + sb;
    const int k0 = ks * 32 + (lane >> 4) * 8;
    ws[g] = cvt8(mw3 + (size_t)n * 128 + k0);
  }
}

template<bool WS>
__device__ __forceinline__ f16x8 ldB(const f16x8* __restrict__ wp,
                                     const float* __restrict__ wf,
                                     int K, int n0, int ks, int lane) {
  if constexpr (WS) {
    return wp[((n0 >> 4) * (K >> 5) + ks) * 64 + lane];
  } else {
    const int n  = n0 + (lane & 15);
    const int k0 = ks * 32 + (lane >> 4) * 8;
    return cvt8(wf + (size_t)n * K + k0);
  }
}

template<bool WS>
__device__ __forceinline__ f16x8 ldB3(const f16x8* __restrict__ wp,
                                      const float* __restrict__ wf,
                                      int l, int ch, int tt, int sb, int ks, int lane) {
  if constexpr (WS) {
    const int fb = (((l * 2 + ch) * 4 + tt) * 2 + sb) * 4 + ks;
    return wp[fb * 64 + lane];
  } else {
    const int n  = l * 256 + 2 * (ch * 64 + tt * 16 + (lane & 15)) + sb;
    const int k0 = ks * 32 + (lane >> 4) * 8;
    return cvt8(wf + (size_t)n * 128 + k0);
  }
}

#define MFMA(a, b, c) __builtin_amdgcn_mfma_f32_16x16x32_f16((a), (b), (c), 0, 0, 0)

template<bool WS>
__global__ __launch_bounds__(NTHR, 4)   // target <=128 unified regs -> 4 waves/SIMD
void adain_mfma(const float* __restrict__ x,   const float* __restrict__ meta,
                const float* __restrict__ mw1, const float* __restrict__ mb1,
                const float* __restrict__ mw2, const float* __restrict__ mb2,
                const float* __restrict__ mw3, const float* __restrict__ mb3,
                const float* __restrict__ w1,  const float* __restrict__ b1,
                const float* __restrict__ w2,  const float* __restrict__ b2,
                const float* __restrict__ w3,  const float* __restrict__ b3,
                const float* __restrict__ w4,  const float* __restrict__ b4,
                const float* __restrict__ w5,  const float* __restrict__ b5,
                const f16x8* __restrict__ wsp, float* __restrict__ out)
{
  __shared__ __align__(16) char smem[SMEM_SZ];
  f16    (*sH2)[136]   = (f16(*)[136])  (smem + OFF_H2);
  float  (*sMeta)[16]  = (float(*)[16]) (smem + OFF_META);
  f16    (*sH1)[72]    = (f16(*)[72])   (smem + OFF_H1);
  f16    (*sY)[136]    = (f16(*)[136])  (smem + OFF_B);
  float2 (*sStats)[2]  = (float2(*)[2]) (smem + OFF_STATS);
  float  (*sOut)[2]    = (float(*)[2])  (smem + OFF_OUT);
  float  *sX           = (float*)       (smem + OFF_X);

  const int t    = threadIdx.x;
  const int lane = t & 63;
  const int ch   = t >> 6;            // wave id == column half
  const int r0   = blockIdx.x * RPB;
  const int ln   = lane & 15;         // fragment n / A-row index
  const int bg   = lane >> 4;         // k-subgroup
  const int acol = bg * 8;
  const int g4   = bg * 4;            // D-row base offset

  const f16x8* wsp3 = wsp + GO_MW3;

  // ---- stage metadata + x ----
  ((float4*)&sMeta[0][0])[t] = ((const float4*)(meta + (size_t)r0 * 16))[t];
  if (t < RPB) sX[t] = x[r0 + t];

  // ---- h1 = relu(meta @ mw1.T + mb1) : (32,16)->(32,64), VALU ----
  {
    const int j = t & 63, rg = t >> 6;
    float wr[16];
    const float4* p4 = (const float4*)(mw1 + j * 16);
#pragma unroll
    for (int q = 0; q < 4; ++q) {
      float4 f = p4[q];
      wr[4*q] = f.x; wr[4*q+1] = f.y; wr[4*q+2] = f.z; wr[4*q+3] = f.w;
    }
    const float bj = mb1[j];
#pragma unroll
    for (int rr = 0; rr < 16; ++rr) {
      const int r = rg * 16 + rr;
      float acc = bj;
#pragma unroll
      for (int k = 0; k < 16; ++k) acc += wr[k] * sMeta[r][k];
      sH1[r][j] = (f16)fmaxf(acc, 0.0f);
    }
  }
  __syncthreads();

  // ---- h2 = relu(h1 @ mw2.T + mb2) : MFMA K=64 ----
  {
    f16x8 a0[2], a1[2];
#pragma unroll
    for (int p = 0; p < 2; ++p) {
      const int ar = p * 16 + ln;
      a0[p] = *(const f16x8*)&sH1[ar][acol];
      a1[p] = *(const f16x8*)&sH1[ar][32 + acol];
    }
#pragma unroll
    for (int tt = 0; tt < 4; ++tt) {
      const int n0 = ch * 64 + tt * 16;
      f16x8 b0 = ldB<WS>(wsp + GO_MW2, mw2, 64, n0, 0, lane);
      f16x8 b1 = ldB<WS>(wsp + GO_MW2, mw2, 64, n0, 1, lane);
      const float bias = mb2[n0 + ln];
#pragma unroll
      for (int p = 0; p < 2; ++p) {
        f32x4 acc = {0.f, 0.f, 0.f, 0.f};
        acc = MFMA(a0[p], b0, acc);
        acc = MFMA(a1[p], b1, acc);
        const int dr = p * 16 + g4;
#pragma unroll
        for (int q = 0; q < 4; ++q)
          sH2[dr + q][n0 + ln] = (f16)fmaxf(acc[q] + bias, 0.0f);
      }
    }
  }
  __syncthreads();

  // ---- 4 AdaIN layers: main-first (f32 stats), z->f16 after norm, style per-tt ----
#pragma unroll 1
  for (int l = 0; l < 4; ++l) {
    // ---- phase B: main pre-activation (f32, ks-outer to cut aY residency) ----
    f32x4 accM[2][4];
    float s1[2][4] = {{0,0,0,0},{0,0,0,0}}, s2[2][4] = {{0,0,0,0},{0,0,0,0}};

    if (l == 0) {
#pragma unroll
      for (int tt = 0; tt < 4; ++tt) {
        const int c = ch * 64 + tt * 16 + ln;
        const float w1c = w1[c], b1c = b1[c];
#pragma unroll
        for (int p = 0; p < 2; ++p) {
          const int dr = p * 16 + g4;
#pragma unroll
          for (int q = 0; q < 4; ++q) {
            const float v = sX[dr + q] * w1c + b1c;
            accM[p][tt][q] = v;
            s1[p][q] += v; s2[p][q] += v * v;
          }
        }
      }
    } else {
      const f16x8* Wp_ = (l == 1) ? wsp + GO_W2 : (l == 2) ? wsp + GO_W3 : wsp + GO_W4;
      const float* Wf_ = (l == 1) ? w2 : (l == 2) ? w3 : w4;
      const float* Bv_ = (l == 1) ? b2 : (l == 2) ? b3 : b4;
#pragma unroll
      for (int p = 0; p < 2; ++p)
#pragma unroll
        for (int tt = 0; tt < 4; ++tt)
          accM[p][tt] = (f32x4){0.f, 0.f, 0.f, 0.f};
#pragma unroll
      for (int ks = 0; ks < 4; ++ks) {
        const f16x8 aY0 = *(const f16x8*)&sY[ln][ks * 32 + acol];
        const f16x8 aY1 = *(const f16x8*)&sY[16 + ln][ks * 32 + acol];
#pragma unroll
        for (int tt = 0; tt < 4; ++tt) {
          const f16x8 bm = ldB<WS>(Wp_, Wf_, 128, ch * 64 + tt * 16, ks, lane);
          accM[0][tt] = MFMA(aY0, bm, accM[0][tt]);
          accM[1][tt] = MFMA(aY1, bm, accM[1][tt]);
        }
      }
#pragma unroll
      for (int tt = 0; tt < 4; ++tt) {
        const float bias = Bv_[ch * 64 + tt * 16 + ln];
#pragma unroll
        for (int p = 0; p < 2; ++p)
#pragma unroll
          for (int q = 0; q < 4; ++q) {
            const float v = accM[p][tt][q] + bias;
            accM[p][tt][q] = v;
            s1[p][q] += v; s2[p][q] += v * v;
          }
      }
    }

    // ---- stats: 16-lane shuffle reduce, cross-ch exchange via LDS ----
#pragma unroll
    for (int m = 1; m < 16; m <<= 1)
#pragma unroll
      for (int p = 0; p < 2; ++p)
#pragma unroll
        for (int q = 0; q < 4; ++q) {
          s1[p][q] += __shfl_xor(s1[p][q], m, 64);
          s2[p][q] += __shfl_xor(s2[p][q], m, 64);
        }
    if (ln == 0) {
#pragma unroll
      for (int p = 0; p < 2; ++p) {
        const int dr = p * 16 + g4;
#pragma unroll
        for (int q = 0; q < 4; ++q)
          sStats[dr + q][ch] = make_float2(s1[p][q], s2[p][q]);
      }
    }
    __syncthreads();

    // ---- mu/rsg from f32 stats; THEN pack z = (v-mu)*rsg to f16 ----
    f16x4 zh[2][4];
    {
#pragma unroll
      for (int p = 0; p < 2; ++p) {
        const int dr = p * 16 + g4;
#pragma unroll
        for (int q = 0; q < 4; ++q) {
          const float2 A = sStats[dr + q][0], Bc = sStats[dr + q][1];
          const float S1 = A.x + Bc.x, S2 = A.y + Bc.y;
          const float m = S1 * (1.0f / 128.0f);
          float var = (S2 - S1 * m) * (1.0f / 127.0f);
          var = fmaxf(var, 0.0f);
          const float rsg = 1.0f / (sqrtf(var) + 1e-6f);
#pragma unroll
          for (int tt = 0; tt < 4; ++tt)
            zh[p][tt][q] = (f16)((accM[p][tt][q] - m) * rsg);
        }
      }
    }

    // ---- phase A: style MFMA + apply, per tt (scale/bias transient f32) ----
    f16x8 aH[2][4];
#pragma unroll
    for (int p = 0; p < 2; ++p) {
      const int ar = p * 16 + ln;
#pragma unroll
      for (int ks = 0; ks < 4; ++ks)
        aH[p][ks] = *(const f16x8*)&sH2[ar][ks * 32 + acol];
    }

    if (l < 3) {
#pragma unroll
      for (int tt = 0; tt < 4; ++tt) {
        const int c = ch * 64 + tt * 16 + ln;
        const float2 mbt = *(const float2*)(mb3 + l * 256 + 2 * c);
        f32x4 sc0 = {0.f,0.f,0.f,0.f}, sc1 = {0.f,0.f,0.f,0.f};
        f32x4 bi0 = {0.f,0.f,0.f,0.f}, bi1 = {0.f,0.f,0.f,0.f};
#pragma unroll
        for (int ks = 0; ks < 4; ++ks) {
          const f16x8 bs0 = ldB3<WS>(wsp3, mw3, l, ch, tt, 0, ks, lane);
          const f16x8 bs1 = ldB3<WS>(wsp3, mw3, l, ch, tt, 1, ks, lane);
          sc0 = MFMA(aH[0][ks], bs0, sc0);
          sc1 = MFMA(aH[1][ks], bs0, sc1);
          bi0 = MFMA(aH[0][ks], bs1, bi0);
          bi1 = MFMA(aH[1][ks], bs1, bi1);
        }
#pragma unroll
        for (int p = 0; p < 2; ++p) {
          const int dr = p * 16 + g4;
          const f32x4 scp = p ? sc1 : sc0;
          const f32x4 bip = p ? bi1 : bi0;
#pragma unroll
          for (int q = 0; q < 4; ++q) {
            float v = (scp[q] + mbt.x) * (float)zh[p][tt][q] + (bip[q] + mbt.y);
            v = fmaxf(v, 0.01f * v);
            sY[dr + q][c] = (f16)v;
          }
        }
      }
      __syncthreads();
    } else {
      float o[2][4] = {{0,0,0,0},{0,0,0,0}};
#pragma unroll
      for (int tt = 0; tt < 4; ++tt) {
        const int c = ch * 64 + tt * 16 + ln;
        const float2 mbt = *(const float2*)(mb3 + l * 256 + 2 * c);
        const float w5c = w5[c];
        f32x4 sc0 = {0.f,0.f,0.f,0.f}, sc1 = {0.f,0.f,0.f,0.f};
        f32x4 bi0 = {0.f,0.f,0.f,0.f}, bi1 = {0.f,0.f,0.f,0.f};
#pragma unroll
        for (int ks = 0; ks < 4; ++ks) {
          const f16x8 bs0 = ldB3<WS>(wsp3, mw3, l, ch, tt, 0, ks, lane);
          const f16x8 bs1 = ldB3<WS>(wsp3, mw3, l, ch, tt, 1, ks, lane);
          sc0 = MFMA(aH[0][ks], bs0, sc0);
          sc1 = MFMA(aH[1][ks], bs0, sc1);
          bi0 = MFMA(aH[0][ks], bs1, bi0);
          bi1 = MFMA(aH[1][ks], bs1, bi1);
        }
#pragma unroll
        for (int p = 0; p < 2; ++p) {
          const f32x4 scp = p ? sc1 : sc0;
          const f32x4 bip = p ? bi1 : bi0;
#pragma unroll
          for (int q = 0; q < 4; ++q) {
            float v = (scp[q] + mbt.x) * (float)zh[p][tt][q] + (bip[q] + mbt.y);
            v = fmaxf(v, 0.01f * v);
            o[p][q] += v * w5c;
          }
        }
      }
#pragma unroll
      for (int m = 1; m < 16; m <<= 1)
#pragma unroll
        for (int p = 0; p < 2; ++p)
#pragma unroll
          for (int q = 0; q < 4; ++q) o[p][q] += __shfl_xor(o[p][q], m, 64);
      if (ln == 0) {
#pragma unroll
        for (int p = 0; p < 2; ++p) {
          const int dr = p * 16 + g4;
#pragma unroll
          for (int q = 0; q < 4; ++q) sOut[dr + q][ch] = o[p][q];
        }
      }
      __syncthreads();
      if (t < RPB) {
        float v = sOut[t][0] + sOut[t][1] + b5[0];
        v = fmaxf(v, 0.01f * v);
        out[r0 + t] = v;
      }
    }
  }
}

extern "C" void kernel_launch(void* const* d_in, const int* in_sizes, int n_in,
                              void* d_out, int out_size, void* d_ws, size_t ws_size,
                              hipStream_t stream) {
  const float* x    = (const float*)d_in[0];
  const float* meta = (const float*)d_in[1];
  const float* mw1  = (const float*)d_in[2];
  const float* mb1  = (const float*)d_in[3];
  const float* mw2  = (const float*)d_in[4];
  const float* mb2  = (const float*)d_in[5];
  const float* mw3  = (const float*)d_in[6];
  const float* mb3  = (const float*)d_in[7];
  const float* w1   = (const float*)d_in[8];
  const float* b1   = (const float*)d_in[9];
  const float* w2   = (const float*)d_in[10];
  const float* b2   = (const float*)d_in[11];
  const float* w3   = (const float*)d_in[12];
  const float* b3   = (const float*)d_in[13];
  const float* w4   = (const float*)d_in[14];
  const float* b4   = (const float*)d_in[15];
  const float* w5   = (const float*)d_in[16];
  const float* b5   = (const float*)d_in[17];
  float* out = (float*)d_out;

  const int nrows = in_sizes[0];        // 262144
  const int grid  = nrows / RPB;        // 8192

  const bool usews = (ws_size >= WS_BYTES) && (d_ws != nullptr);
  if (usews) {
    f16x8* wsp = (f16x8*)d_ws;
    hipLaunchKernelGGL(pack_weights, dim3((G_TOT + 255) / 256), dim3(256), 0, stream,
                       mw2, w2, w3, w4, mw3, wsp);
    hipLaunchKernelGGL(adain_mfma<true>, dim3(grid), dim3(NTHR), 0, stream,
                       x, meta, mw1, mb1, mw2, mb2, mw3, mb3,
                       w1, b1, w2, b2, w3, b3, w4, b4, w5, b5, wsp, out);
  } else {
    hipLaunchKernelGGL(adain_mfma<false>, dim3(grid), dim3(NTHR), 0, stream,
                       x, meta, mw1, mb1, mw2, mb2, mw3, mb3,
                       w1, b1, w2, b2, w3, b3, w4, b4, w5, b5, (const f16x8*)nullptr, out);
  }
}

// Round 12
// 218.531 us; speedup vs baseline: 1.7882x; 1.3077x over previous
//
#include <hip/hip_runtime.h>

#define RPB  64     // rows per block
#define NTHR 128    // 2 waves: ch = wid (0..1); each wave 64 rows x 64 cols

typedef _Float16 f16;
typedef _Float16 f16x2 __attribute__((ext_vector_type(2)));
typedef _Float16 f16x4 __attribute__((ext_vector_type(4)));
typedef _Float16 f16x8 __attribute__((ext_vector_type(8)));
typedef float    f32x4 __attribute__((ext_vector_type(4)));

// ---- workspace layout: weights packed to f16 in B-fragment order ----
#define G_MW2 1024                 // 128*64/8
#define G_W   2048                 // 128*128/8
#define G_MW3 16384                // 1024*128/8
#define GO_MW2 0
#define GO_W2  (GO_MW2 + G_MW2)
#define GO_W3  (GO_W2 + G_W)
#define GO_W4  (GO_W3 + G_W)
#define GO_MW3 (GO_W4 + G_W)
#define G_TOT  (GO_MW3 + G_MW3)    // 23552 groups
#define WS_BYTES ((size_t)G_TOT * 16)

// ---- LDS layout (bytes), per 64-row block ----
#define OFF_H2    0
#define OFF_B     17408
#define OFF_META  (OFF_B)
#define OFF_H1    (OFF_B + 4096)
#define OFF_STATS (OFF_B + 17408)      // 34816
#define OFF_OUT   (OFF_STATS + 1024)   // 35840
#define OFF_X     (OFF_OUT + 512)      // 36352
#define SMEM_SZ   (OFF_X + 256)        // 36608

__device__ __forceinline__ f16x8 cvt8(const float* __restrict__ p) {
  const float4* p4 = (const float4*)p;
  float4 f0 = p4[0], f1 = p4[1];
  f16x8 o;
  o[0]=(f16)f0.x; o[1]=(f16)f0.y; o[2]=(f16)f0.z; o[3]=(f16)f0.w;
  o[4]=(f16)f1.x; o[5]=(f16)f1.y; o[6]=(f16)f1.z; o[7]=(f16)f1.w;
  return o;
}

__global__ void pack_weights(const float* __restrict__ mw2, const float* __restrict__ w2,
                             const float* __restrict__ w3,  const float* __restrict__ w4,
                             const float* __restrict__ mw3, f16x8* __restrict__ ws) {
  int g = blockIdx.x * blockDim.x + threadIdx.x;
  if (g >= G_TOT) return;
  if (g < GO_MW3) {                 // linear-packed matrices
    const float* W; int K; int local;
    if (g < GO_W2)       { W = mw2; K = 64;  local = g; }
    else if (g < GO_W3)  { W = w2;  K = 128; local = g - GO_W2; }
    else if (g < GO_W4)  { W = w3;  K = 128; local = g - GO_W3; }
    else                 { W = w4;  K = 128; local = g - GO_W4; }
    const int lane = local & 63, fb = local >> 6;
    const int ksteps = K >> 5;
    const int ks = fb % ksteps, n0g = fb / ksteps;
    const int n  = n0g * 16 + (lane & 15);
    const int k0 = ks * 32 + (lane >> 4) * 8;
    ws[g] = cvt8(W + (size_t)n * K + k0);
  } else {                          // mw3: AdaIN-interleaved
    const int local = g - GO_MW3;
    const int lane = local & 63, fb = local >> 6;   // fb: l(2) ch(1) tt(2) sb(1) ks(2)
    const int ks = fb & 3, sb = (fb >> 2) & 1, tt = (fb >> 3) & 3;
    const int ch = (fb >> 5) & 1, l = fb >> 6;
    const int n  = l * 256 + 2 * (ch * 64 + tt * 16 + (lane & 15)) + sb;
    const int k0 = ks * 32 + (lane >> 4) * 8;
    ws[g] = cvt8(mw3 + (size_t)n * 128 + k0);
  }
}

template<bool WS>
__device__ __forceinline__ f16x8 ldB(const f16x8* __restrict__ wp,
                                     const float* __restrict__ wf,
                                     int K, int n0, int ks, int lane) {
  if constexpr (WS) {
    return wp[((n0 >> 4) * (K >> 5) + ks) * 64 + lane];
  } else {
    const int n  = n0 + (lane & 15);
    const int k0 = ks * 32 + (lane >> 4) * 8;
    return cvt8(wf + (size_t)n * K + k0);
  }
}

template<bool WS>
__device__ __forceinline__ f16x8 ldB3(const f16x8* __restrict__ wp,
                                      const float* __restrict__ wf,
                                      int l, int ch, int tt, int sb, int ks, int lane) {
  if constexpr (WS) {
    const int fb = (((l * 2 + ch) * 4 + tt) * 2 + sb) * 4 + ks;
    return wp[fb * 64 + lane];
  } else {
    const int n  = l * 256 + 2 * (ch * 64 + tt * 16 + (lane & 15)) + sb;
    const int k0 = ks * 32 + (lane >> 4) * 8;
    return cvt8(wf + (size_t)n * 128 + k0);
  }
}

#define MFMA(a, b, c) __builtin_amdgcn_mfma_f32_16x16x32_f16((a), (b), (c), 0, 0, 0)

template<bool WS>
__global__ __launch_bounds__(NTHR, 2)   // 2 waves/EU band (<=256 regs) — no spill
void adain_mfma(const float* __restrict__ x,   const float* __restrict__ meta,
                const float* __restrict__ mw1, const float* __restrict__ mb1,
                const float* __restrict__ mw2, const float* __restrict__ mb2,
                const float* __restrict__ mw3, const float* __restrict__ mb3,
                const float* __restrict__ w1,  const float* __restrict__ b1,
                const float* __restrict__ w2,  const float* __restrict__ b2,
                const float* __restrict__ w3,  const float* __restrict__ b3,
                const float* __restrict__ w4,  const float* __restrict__ b4,
                const float* __restrict__ w5,  const float* __restrict__ b5,
                const f16x8* __restrict__ wsp, float* __restrict__ out)
{
  __shared__ __align__(16) char smem[SMEM_SZ];
  f16    (*sH2)[136]   = (f16(*)[136])  (smem + OFF_H2);
  float  (*sMeta)[16]  = (float(*)[16]) (smem + OFF_META);
  f16    (*sH1)[72]    = (f16(*)[72])   (smem + OFF_H1);
  f16    (*sY)[136]    = (f16(*)[136])  (smem + OFF_B);
  float2 (*sStats)[2]  = (float2(*)[2]) (smem + OFF_STATS);
  float  (*sOut)[2]    = (float(*)[2])  (smem + OFF_OUT);
  float  *sX           = (float*)       (smem + OFF_X);

  const int t    = threadIdx.x;
  const int lane = t & 63;
  const int ch   = t >> 6;            // wave id == column half
  const int r0   = blockIdx.x * RPB;
  const int ln   = lane & 15;         // fragment n / A-row index
  const int bg   = lane >> 4;         // k-subgroup
  const int acol = bg * 8;
  const int g4   = bg * 4;            // D-row base offset

  const f16x8* wsp3 = wsp + GO_MW3;

  // ---- stage metadata + x ----
  {
    const float4* mp = (const float4*)(meta + (size_t)r0 * 16);
    ((float4*)&sMeta[0][0])[t]       = mp[t];
    ((float4*)&sMeta[0][0])[t + 128] = mp[t + 128];
    if (t < RPB) sX[t] = x[r0 + t];
  }
  __syncthreads();   // R11 bug fix: h1 rows 16-31/48-63 are staged by the OTHER wave

  // ---- h1 = relu(meta @ mw1.T + mb1) : (64,16)->(64,64), VALU ----
  {
    const int j = t & 63, rg = t >> 6;
    float wr[16];
    const float4* p4 = (const float4*)(mw1 + j * 16);
#pragma unroll
    for (int q = 0; q < 4; ++q) {
      float4 f = p4[q];
      wr[4*q] = f.x; wr[4*q+1] = f.y; wr[4*q+2] = f.z; wr[4*q+3] = f.w;
    }
    const float bj = mb1[j];
#pragma unroll
    for (int rr = 0; rr < 32; ++rr) {
      const int r = rg * 32 + rr;
      float acc = bj;
#pragma unroll
      for (int k = 0; k < 16; ++k) acc += wr[k] * sMeta[r][k];
      sH1[r][j] = (f16)fmaxf(acc, 0.0f);
    }
  }
  __syncthreads();

  // ---- h2 = relu(h1 @ mw2.T + mb2) : MFMA K=64, wave: 64 rows x 64 cols ----
  {
    f16x8 a0[4], a1[4];
#pragma unroll
    for (int p = 0; p < 4; ++p) {
      const int ar = p * 16 + ln;
      a0[p] = *(const f16x8*)&sH1[ar][acol];
      a1[p] = *(const f16x8*)&sH1[ar][32 + acol];
    }
#pragma unroll
    for (int tt = 0; tt < 4; ++tt) {
      const int n0 = ch * 64 + tt * 16;
      f16x8 b0 = ldB<WS>(wsp + GO_MW2, mw2, 64, n0, 0, lane);
      f16x8 b1 = ldB<WS>(wsp + GO_MW2, mw2, 64, n0, 1, lane);
      const float bias = mb2[n0 + ln];
#pragma unroll
      for (int p = 0; p < 4; ++p) {
        f32x4 acc = {0.f, 0.f, 0.f, 0.f};
        acc = MFMA(a0[p], b0, acc);
        acc = MFMA(a1[p], b1, acc);
        const int dr = p * 16 + g4;
#pragma unroll
        for (int q = 0; q < 4; ++q)
          sH2[dr + q][n0 + ln] = (f16)fmaxf(acc[q] + bias, 0.0f);
      }
    }
  }
  __syncthreads();

  // ---- 4 AdaIN layers: main-first (f32 stats), z->f16 after norm, style per-tt ----
#pragma unroll 1
  for (int l = 0; l < 4; ++l) {
    // ---- phase B: main pre-activation (f32, ks-outer; accM[4 stripes][4 tt]) ----
    f32x4 accM[4][4];

    if (l == 0) {
#pragma unroll
      for (int tt = 0; tt < 4; ++tt) {
        const int c = ch * 64 + tt * 16 + ln;
        const float w1c = w1[c], b1c = b1[c];
#pragma unroll
        for (int p = 0; p < 4; ++p) {
          const int dr = p * 16 + g4;
#pragma unroll
          for (int q = 0; q < 4; ++q)
            accM[p][tt][q] = sX[dr + q] * w1c + b1c;
        }
      }
    } else {
      const f16x8* Wp_ = (l == 1) ? wsp + GO_W2 : (l == 2) ? wsp + GO_W3 : wsp + GO_W4;
      const float* Wf_ = (l == 1) ? w2 : (l == 2) ? w3 : w4;
      const float* Bv_ = (l == 1) ? b2 : (l == 2) ? b3 : b4;
#pragma unroll
      for (int p = 0; p < 4; ++p)
#pragma unroll
        for (int tt = 0; tt < 4; ++tt)
          accM[p][tt] = (f32x4){0.f, 0.f, 0.f, 0.f};
#pragma unroll
      for (int ks = 0; ks < 4; ++ks) {
        f16x8 aY[4];
#pragma unroll
        for (int p = 0; p < 4; ++p)
          aY[p] = *(const f16x8*)&sY[p * 16 + ln][ks * 32 + acol];
#pragma unroll
        for (int tt = 0; tt < 4; ++tt) {
          const f16x8 bm = ldB<WS>(Wp_, Wf_, 128, ch * 64 + tt * 16, ks, lane);
#pragma unroll
          for (int p = 0; p < 4; ++p)
            accM[p][tt] = MFMA(aY[p], bm, accM[p][tt]);
        }
      }
#pragma unroll
      for (int tt = 0; tt < 4; ++tt) {
        const float bias = Bv_[ch * 64 + tt * 16 + ln];
#pragma unroll
        for (int p = 0; p < 4; ++p)
#pragma unroll
          for (int q = 0; q < 4; ++q)
            accM[p][tt][q] += bias;
      }
    }

    // ---- stats per stripe: 16-lane shuffle reduce, cross-ch via LDS ----
#pragma unroll
    for (int p = 0; p < 4; ++p) {
      float s1[4] = {0,0,0,0}, s2[4] = {0,0,0,0};
#pragma unroll
      for (int tt = 0; tt < 4; ++tt)
#pragma unroll
        for (int q = 0; q < 4; ++q) {
          const float v = accM[p][tt][q];
          s1[q] += v; s2[q] += v * v;
        }
#pragma unroll
      for (int m = 1; m < 16; m <<= 1)
#pragma unroll
        for (int q = 0; q < 4; ++q) {
          s1[q] += __shfl_xor(s1[q], m, 64);
          s2[q] += __shfl_xor(s2[q], m, 64);
        }
      if (ln == 0) {
        const int dr = p * 16 + g4;
#pragma unroll
        for (int q = 0; q < 4; ++q)
          sStats[dr + q][ch] = make_float2(s1[q], s2[q]);
      }
    }
    __syncthreads();

    // ---- mu/rsg from f32 stats; THEN pack z = (v-mu)*rsg to f16 ----
    f16x4 zh[4][4];
#pragma unroll
    for (int p = 0; p < 4; ++p) {
      const int dr = p * 16 + g4;
#pragma unroll
      for (int q = 0; q < 4; ++q) {
        const float2 A = sStats[dr + q][0], Bc = sStats[dr + q][1];
        const float S1 = A.x + Bc.x, S2 = A.y + Bc.y;
        const float m = S1 * (1.0f / 128.0f);
        float var = (S2 - S1 * m) * (1.0f / 127.0f);
        var = fmaxf(var, 0.0f);
        const float rsg = 1.0f / (sqrtf(var) + 1e-6f);
#pragma unroll
        for (int tt = 0; tt < 4; ++tt)
          zh[p][tt][q] = (f16)((accM[p][tt][q] - m) * rsg);
      }
    }

    // ---- phase A: style MFMA + apply, per tt (sc/bi transient) ----
    f16x8 aH[4][4];
#pragma unroll
    for (int p = 0; p < 4; ++p) {
      const int ar = p * 16 + ln;
#pragma unroll
      for (int ks = 0; ks < 4; ++ks)
        aH[p][ks] = *(const f16x8*)&sH2[ar][ks * 32 + acol];
    }

    if (l < 3) {
#pragma unroll
      for (int tt = 0; tt < 4; ++tt) {
        const int c = ch * 64 + tt * 16 + ln;
        const float2 mbt = *(const float2*)(mb3 + l * 256 + 2 * c);
        f32x4 sc[4], bi[4];
#pragma unroll
        for (int p = 0; p < 4; ++p) {
          sc[p] = (f32x4){0.f,0.f,0.f,0.f};
          bi[p] = (f32x4){0.f,0.f,0.f,0.f};
        }
#pragma unroll
        for (int ks = 0; ks < 4; ++ks) {
          const f16x8 bs0 = ldB3<WS>(wsp3, mw3, l, ch, tt, 0, ks, lane);
          const f16x8 bs1 = ldB3<WS>(wsp3, mw3, l, ch, tt, 1, ks, lane);
#pragma unroll
          for (int p = 0; p < 4; ++p) {
            sc[p] = MFMA(aH[p][ks], bs0, sc[p]);
            bi[p] = MFMA(aH[p][ks], bs1, bi[p]);
          }
        }
#pragma unroll
        for (int p = 0; p < 4; ++p) {
          const int dr = p * 16 + g4;
#pragma unroll
          for (int q = 0; q < 4; ++q) {
            float v = (sc[p][q] + mbt.x) * (float)zh[p][tt][q] + (bi[p][q] + mbt.y);
            v = fmaxf(v, 0.01f * v);
            sY[dr + q][c] = (f16)v;
          }
        }
      }
      __syncthreads();
    } else {
      float o[4][4] = {{0,0,0,0},{0,0,0,0},{0,0,0,0},{0,0,0,0}};
#pragma unroll
      for (int tt = 0; tt < 4; ++tt) {
        const int c = ch * 64 + tt * 16 + ln;
        const float2 mbt = *(const float2*)(mb3 + l * 256 + 2 * c);
        const float w5c = w5[c];
        f32x4 sc[4], bi[4];
#pragma unroll
        for (int p = 0; p < 4; ++p) {
          sc[p] = (f32x4){0.f,0.f,0.f,0.f};
          bi[p] = (f32x4){0.f,0.f,0.f,0.f};
        }
#pragma unroll
        for (int ks = 0; ks < 4; ++ks) {
          const f16x8 bs0 = ldB3<WS>(wsp3, mw3, l, ch, tt, 0, ks, lane);
          const f16x8 bs1 = ldB3<WS>(wsp3, mw3, l, ch, tt, 1, ks, lane);
#pragma unroll
          for (int p = 0; p < 4; ++p) {
            sc[p] = MFMA(aH[p][ks], bs0, sc[p]);
            bi[p] = MFMA(aH[p][ks], bs1, bi[p]);
          }
        }
#pragma unroll
        for (int p = 0; p < 4; ++p)
#pragma unroll
          for (int q = 0; q < 4; ++q) {
            float v = (sc[p][q] + mbt.x) * (float)zh[p][tt][q] + (bi[p][q] + mbt.y);
            v = fmaxf(v, 0.01f * v);
            o[p][q] += v * w5c;
          }
      }
#pragma unroll
      for (int m = 1; m < 16; m <<= 1)
#pragma unroll
        for (int p = 0; p < 4; ++p)
#pragma unroll
          for (int q = 0; q < 4; ++q) o[p][q] += __shfl_xor(o[p][q], m, 64);
      if (ln == 0) {
#pragma unroll
        for (int p = 0; p < 4; ++p) {
          const int dr = p * 16 + g4;
#pragma unroll
          for (int q = 0; q < 4; ++q) sOut[dr + q][ch] = o[p][q];
        }
      }
      __syncthreads();
      if (t < RPB) {
        float v = sOut[t][0] + sOut[t][1] + b5[0];
        v = fmaxf(v, 0.01f * v);
        out[r0 + t] = v;
      }
    }
  }
}

extern "C" void kernel_launch(void* const* d_in, const int* in_sizes, int n_in,
                              void* d_out, int out_size, void* d_ws, size_t ws_size,
                              hipStream_t stream) {
  const float* x    = (const float*)d_in[0];
  const float* meta = (const float*)d_in[1];
  const float* mw1  = (const float*)d_in[2];
  const float* mb1  = (const float*)d_in[3];
  const float* mw2  = (const float*)d_in[4];
  const float* mb2  = (const float*)d_in[5];
  const float* mw3  = (const float*)d_in[6];
  const float* mb3  = (const float*)d_in[7];
  const float* w1   = (const float*)d_in[8];
  const float* b1   = (const float*)d_in[9];
  const float* w2   = (const float*)d_in[10];
  const float* b2   = (const float*)d_in[11];
  const float* w3   = (const float*)d_in[12];
  const float* b3   = (const float*)d_in[13];
  const float* w4   = (const float*)d_in[14];
  const float* b4   = (const float*)d_in[15];
  const float* w5   = (const float*)d_in[16];
  const float* b5   = (const float*)d_in[17];
  float* out = (float*)d_out;

  const int nrows = in_sizes[0];        // 262144
  const int grid  = nrows / RPB;        // 4096

  const bool usews = (ws_size >= WS_BYTES) && (d_ws != nullptr);
  if (usews) {
    f16x8* wsp = (f16x8*)d_ws;
    hipLaunchKernelGGL(pack_weights, dim3((G_TOT + 255) / 256), dim3(256), 0, stream,
                       mw2, w2, w3, w4, mw3, wsp);
    hipLaunchKernelGGL(adain_mfma<true>, dim3(grid), dim3(NTHR), 0, stream,
                       x, meta, mw1, mb1, mw2, mb2, mw3, mb3,
                       w1, b1, w2, b2, w3, b3, w4, b4, w5, b5, wsp, out);
  } else {
    hipLaunchKernelGGL(adain_mfma<false>, dim3(grid), dim3(NTHR), 0, stream,
                       x, meta, mw1, mb1, mw2, mb2, mw3, mb3,
                       w1, b1, w2, b2, w3, b3, w4, b4, w5, b5, (const f16x8*)nullptr, out);
  }
}

// Round 13
// 171.074 us; speedup vs baseline: 2.2843x; 1.2774x over previous
//
#include <hip/hip_runtime.h>

#define RPB  64     // rows per block
#define NTHR 128    // 2 waves: ch = wid (0..1); each wave 64 rows x 64 cols

typedef _Float16 f16;
typedef _Float16 f16x2 __attribute__((ext_vector_type(2)));
typedef _Float16 f16x4 __attribute__((ext_vector_type(4)));
typedef _Float16 f16x8 __attribute__((ext_vector_type(8)));
typedef float    f32x4 __attribute__((ext_vector_type(4)));

// ---- workspace layout: weights packed to f16 in B-fragment order ----
#define G_MW2 1024                 // 128*64/8
#define G_W   2048                 // 128*128/8
#define G_MW3 16384                // 1024*128/8
#define GO_MW2 0
#define GO_W2  (GO_MW2 + G_MW2)
#define GO_W3  (GO_W2 + G_W)
#define GO_W4  (GO_W3 + G_W)
#define GO_MW3 (GO_W4 + G_W)
#define G_TOT  (GO_MW3 + G_MW3)    // 23552 groups
#define WS_BYTES ((size_t)G_TOT * 16)

// ---- LDS layout (bytes), per 64-row block ----
#define OFF_H2    0
#define OFF_B     17408
#define OFF_META  (OFF_B)
#define OFF_H1    (OFF_B + 4096)
#define OFF_STATS (OFF_B + 17408)      // 34816
#define OFF_OUT   (OFF_STATS + 1024)   // 35840
#define OFF_X     (OFF_OUT + 512)      // 36352
#define SMEM_SZ   (OFF_X + 256)        // 36608

__device__ __forceinline__ f16x8 cvt8(const float* __restrict__ p) {
  const float4* p4 = (const float4*)p;
  float4 f0 = p4[0], f1 = p4[1];
  f16x8 o;
  o[0]=(f16)f0.x; o[1]=(f16)f0.y; o[2]=(f16)f0.z; o[3]=(f16)f0.w;
  o[4]=(f16)f1.x; o[5]=(f16)f1.y; o[6]=(f16)f1.z; o[7]=(f16)f1.w;
  return o;
}

__global__ void pack_weights(const float* __restrict__ mw2, const float* __restrict__ w2,
                             const float* __restrict__ w3,  const float* __restrict__ w4,
                             const float* __restrict__ mw3, f16x8* __restrict__ ws) {
  int g = blockIdx.x * blockDim.x + threadIdx.x;
  if (g >= G_TOT) return;
  if (g < GO_MW3) {                 // linear-packed matrices
    const float* W; int K; int local;
    if (g < GO_W2)       { W = mw2; K = 64;  local = g; }
    else if (g < GO_W3)  { W = w2;  K = 128; local = g - GO_W2; }
    else if (g < GO_W4)  { W = w3;  K = 128; local = g - GO_W3; }
    else                 { W = w4;  K = 128; local = g - GO_W4; }
    const int lane = local & 63, fb = local >> 6;
    const int ksteps = K >> 5;
    const int ks = fb % ksteps, n0g = fb / ksteps;
    const int n  = n0g * 16 + (lane & 15);
    const int k0 = ks * 32 + (lane >> 4) * 8;
    ws[g] = cvt8(W + (size_t)n * K + k0);
  } else {                          // mw3: AdaIN-interleaved
    const int local = g - GO_MW3;
    const int lane = local & 63, fb = local >> 6;   // fb: l(2) ch(1) tt(2) sb(1) ks(2)
    const int ks = fb & 3, sb = (fb >> 2) & 1, tt = (fb >> 3) & 3;
    const int ch = (fb >> 5) & 1, l = fb >> 6;
    const int n  = l * 256 + 2 * (ch * 64 + tt * 16 + (lane & 15)) + sb;
    const int k0 = ks * 32 + (lane >> 4) * 8;
    ws[g] = cvt8(mw3 + (size_t)n * 128 + k0);
  }
}

template<bool WS>
__device__ __forceinline__ f16x8 ldB(const f16x8* __restrict__ wp,
                                     const float* __restrict__ wf,
                                     int K, int n0, int ks, int lane) {
  if constexpr (WS) {
    return wp[((n0 >> 4) * (K >> 5) + ks) * 64 + lane];
  } else {
    const int n  = n0 + (lane & 15);
    const int k0 = ks * 32 + (lane >> 4) * 8;
    return cvt8(wf + (size_t)n * K + k0);
  }
}

template<bool WS>
__device__ __forceinline__ f16x8 ldB3(const f16x8* __restrict__ wp,
                                      const float* __restrict__ wf,
                                      int l, int ch, int tt, int sb, int ks, int lane) {
  if constexpr (WS) {
    const int fb = (((l * 2 + ch) * 4 + tt) * 2 + sb) * 4 + ks;
    return wp[fb * 64 + lane];
  } else {
    const int n  = l * 256 + 2 * (ch * 64 + tt * 16 + (lane & 15)) + sb;
    const int k0 = ks * 32 + (lane >> 4) * 8;
    return cvt8(wf + (size_t)n * 128 + k0);
  }
}

#define MFMA(a, b, c) __builtin_amdgcn_mfma_f32_16x16x32_f16((a), (b), (c), 0, 0, 0)

template<bool WS>
__global__ __launch_bounds__(NTHR, 2)   // 2 waves/EU band (<=256 regs)
void adain_mfma(const float* __restrict__ x,   const float* __restrict__ meta,
                const float* __restrict__ mw1, const float* __restrict__ mb1,
                const float* __restrict__ mw2, const float* __restrict__ mb2,
                const float* __restrict__ mw3, const float* __restrict__ mb3,
                const float* __restrict__ w1,  const float* __restrict__ b1,
                const float* __restrict__ w2,  const float* __restrict__ b2,
                const float* __restrict__ w3,  const float* __restrict__ b3,
                const float* __restrict__ w4,  const float* __restrict__ b4,
                const float* __restrict__ w5,  const float* __restrict__ b5,
                const f16x8* __restrict__ wsp, float* __restrict__ out)
{
  __shared__ __align__(16) char smem[SMEM_SZ];
  f16    (*sH2)[136]   = (f16(*)[136])  (smem + OFF_H2);
  float  (*sMeta)[16]  = (float(*)[16]) (smem + OFF_META);
  f16    (*sH1)[72]    = (f16(*)[72])   (smem + OFF_H1);
  f16    (*sY)[136]    = (f16(*)[136])  (smem + OFF_B);
  float2 (*sStats)[2]  = (float2(*)[2]) (smem + OFF_STATS);
  float  (*sOut)[2]    = (float(*)[2])  (smem + OFF_OUT);
  float  *sX           = (float*)       (smem + OFF_X);

  const int t    = threadIdx.x;
  const int lane = t & 63;
  const int ch   = t >> 6;            // wave id == column half
  const int r0   = blockIdx.x * RPB;
  const int ln   = lane & 15;         // row index within 16-row stripe (D^T layout)
  const int bg   = lane >> 4;         // k-subgroup / channel quad
  const int acol = bg * 8;
  const int g4   = bg * 4;            // channel base offset within 16-chan tile

  const f16x8* wsp3 = wsp + GO_MW3;

  // ---- stage metadata + x ----
  {
    const float4* mp = (const float4*)(meta + (size_t)r0 * 16);
    ((float4*)&sMeta[0][0])[t]       = mp[t];
    ((float4*)&sMeta[0][0])[t + 128] = mp[t + 128];
    if (t < RPB) sX[t] = x[r0 + t];
  }
  __syncthreads();   // other wave's staging feeds our h1 rows

  // ---- h1 = relu(meta @ mw1.T + mb1) : (64,16)->(64,64), VALU ----
  {
    const int j = t & 63, rg = t >> 6;
    float wr[16];
    const float4* p4 = (const float4*)(mw1 + j * 16);
#pragma unroll
    for (int q = 0; q < 4; ++q) {
      float4 f = p4[q];
      wr[4*q] = f.x; wr[4*q+1] = f.y; wr[4*q+2] = f.z; wr[4*q+3] = f.w;
    }
    const float bj = mb1[j];
#pragma unroll
    for (int rr = 0; rr < 32; ++rr) {
      const int r = rg * 32 + rr;
      float acc = bj;
#pragma unroll
      for (int k = 0; k < 16; ++k) acc += wr[k] * sMeta[r][k];
      sH1[r][j] = (f16)fmaxf(acc, 0.0f);
    }
  }
  __syncthreads();

  // ---- h2 = relu(h1 @ mw2.T + mb2), transposed-D: lane holds 4 chans x 1 row ----
  {
    f16x8 a0[4], a1[4];
#pragma unroll
    for (int p = 0; p < 4; ++p) {
      const int ar = p * 16 + ln;
      a0[p] = *(const f16x8*)&sH1[ar][acol];
      a1[p] = *(const f16x8*)&sH1[ar][32 + acol];
    }
#pragma unroll
    for (int tt = 0; tt < 4; ++tt) {
      const int n0 = ch * 64 + tt * 16;
      f16x8 b0 = ldB<WS>(wsp + GO_MW2, mw2, 64, n0, 0, lane);
      f16x8 b1 = ldB<WS>(wsp + GO_MW2, mw2, 64, n0, 1, lane);
      const float4 bb = *(const float4*)(mb2 + n0 + g4);
#pragma unroll
      for (int p = 0; p < 4; ++p) {
        f32x4 acc = {0.f, 0.f, 0.f, 0.f};
        acc = MFMA(b0, a0[p], acc);      // D^T: row=channel, col=row-index
        acc = MFMA(b1, a1[p], acc);
        f16x4 hv;
        hv[0] = (f16)fmaxf(acc[0] + bb.x, 0.0f);
        hv[1] = (f16)fmaxf(acc[1] + bb.y, 0.0f);
        hv[2] = (f16)fmaxf(acc[2] + bb.z, 0.0f);
        hv[3] = (f16)fmaxf(acc[3] + bb.w, 0.0f);
        *(f16x4*)&sH2[p * 16 + ln][n0 + g4] = hv;
      }
    }
  }
  __syncthreads();

  // ---- 4 AdaIN layers: main-first (f32 stats), z->f16 post-norm, style per-tt ----
#pragma unroll 1
  for (int l = 0; l < 4; ++l) {
    // ---- phase B: main pre-activation (transposed-D) ----
    f32x4 accM[4][4];

    if (l == 0) {
#pragma unroll
      for (int tt = 0; tt < 4; ++tt) {
        const int c4 = ch * 64 + tt * 16 + g4;
        const float4 w1v = *(const float4*)(w1 + c4);
        const float4 b1v = *(const float4*)(b1 + c4);
#pragma unroll
        for (int p = 0; p < 4; ++p) {
          const float xv = sX[p * 16 + ln];
          accM[p][tt][0] = xv * w1v.x + b1v.x;
          accM[p][tt][1] = xv * w1v.y + b1v.y;
          accM[p][tt][2] = xv * w1v.z + b1v.z;
          accM[p][tt][3] = xv * w1v.w + b1v.w;
        }
      }
    } else {
      const f16x8* Wp_ = (l == 1) ? wsp + GO_W2 : (l == 2) ? wsp + GO_W3 : wsp + GO_W4;
      const float* Wf_ = (l == 1) ? w2 : (l == 2) ? w3 : w4;
      const float* Bv_ = (l == 1) ? b2 : (l == 2) ? b3 : b4;
#pragma unroll
      for (int p = 0; p < 4; ++p)
#pragma unroll
        for (int tt = 0; tt < 4; ++tt)
          accM[p][tt] = (f32x4){0.f, 0.f, 0.f, 0.f};
#pragma unroll
      for (int ks = 0; ks < 4; ++ks) {
        f16x8 aY[4];
#pragma unroll
        for (int p = 0; p < 4; ++p)
          aY[p] = *(const f16x8*)&sY[p * 16 + ln][ks * 32 + acol];
#pragma unroll
        for (int tt = 0; tt < 4; ++tt) {
          const f16x8 bm = ldB<WS>(Wp_, Wf_, 128, ch * 64 + tt * 16, ks, lane);
#pragma unroll
          for (int p = 0; p < 4; ++p)
            accM[p][tt] = MFMA(bm, aY[p], accM[p][tt]);
        }
      }
#pragma unroll
      for (int tt = 0; tt < 4; ++tt) {
        const float4 bv = *(const float4*)(Bv_ + ch * 64 + tt * 16 + g4);
#pragma unroll
        for (int p = 0; p < 4; ++p) {
          accM[p][tt][0] += bv.x;
          accM[p][tt][1] += bv.y;
          accM[p][tt][2] += bv.z;
          accM[p][tt][3] += bv.w;
        }
      }
    }

    // ---- stats: all lane values belong to row p*16+ln -> scalar per stripe ----
    float s1[4] = {0,0,0,0}, s2[4] = {0,0,0,0};
#pragma unroll
    for (int p = 0; p < 4; ++p)
#pragma unroll
      for (int tt = 0; tt < 4; ++tt)
#pragma unroll
        for (int q = 0; q < 4; ++q) {
          const float v = accM[p][tt][q];
          s1[p] += v; s2[p] += v * v;
        }
#pragma unroll
    for (int p = 0; p < 4; ++p) {
      s1[p] += __shfl_xor(s1[p], 16, 64);
      s2[p] += __shfl_xor(s2[p], 16, 64);
      s1[p] += __shfl_xor(s1[p], 32, 64);
      s2[p] += __shfl_xor(s2[p], 32, 64);
    }
    if (lane < 16) {
#pragma unroll
      for (int p = 0; p < 4; ++p)
        sStats[p * 16 + ln][ch] = make_float2(s1[p], s2[p]);
    }
    __syncthreads();

    // ---- mu/rsg per stripe (scalars); pack z = (v-mu)*rsg to f16 ----
    f16x4 zh[4][4];
#pragma unroll
    for (int p = 0; p < 4; ++p) {
      const int r = p * 16 + ln;
      const float2 A = sStats[r][0], Bc = sStats[r][1];
      const float S1 = A.x + Bc.x, S2 = A.y + Bc.y;
      const float m = S1 * (1.0f / 128.0f);
      float var = (S2 - S1 * m) * (1.0f / 127.0f);
      var = fmaxf(var, 0.0f);
      const float rsg = 1.0f / (sqrtf(var) + 1e-6f);
#pragma unroll
      for (int tt = 0; tt < 4; ++tt)
#pragma unroll
        for (int q = 0; q < 4; ++q)
          zh[p][tt][q] = (f16)((accM[p][tt][q] - m) * rsg);
    }

    // ---- phase A: style MFMA (transposed) + apply, per tt ----
    f16x8 aH[4][4];
#pragma unroll
    for (int p = 0; p < 4; ++p) {
      const int ar = p * 16 + ln;
#pragma unroll
      for (int ks = 0; ks < 4; ++ks)
        aH[p][ks] = *(const f16x8*)&sH2[ar][ks * 32 + acol];
    }

    if (l < 3) {
#pragma unroll
      for (int tt = 0; tt < 4; ++tt) {
        const int c4 = ch * 64 + tt * 16 + g4;
        const float4 mv0 = *(const float4*)(mb3 + l * 256 + 2 * c4);      // s0 b0 s1 b1
        const float4 mv1 = *(const float4*)(mb3 + l * 256 + 2 * c4 + 4);  // s2 b2 s3 b3
        const float scq[4] = {mv0.x, mv0.z, mv1.x, mv1.z};
        const float biq[4] = {mv0.y, mv0.w, mv1.y, mv1.w};
        f32x4 sc[4], bi[4];
#pragma unroll
        for (int p = 0; p < 4; ++p) {
          sc[p] = (f32x4){0.f,0.f,0.f,0.f};
          bi[p] = (f32x4){0.f,0.f,0.f,0.f};
        }
#pragma unroll
        for (int ks = 0; ks < 4; ++ks) {
          const f16x8 bs0 = ldB3<WS>(wsp3, mw3, l, ch, tt, 0, ks, lane);
          const f16x8 bs1 = ldB3<WS>(wsp3, mw3, l, ch, tt, 1, ks, lane);
#pragma unroll
          for (int p = 0; p < 4; ++p) {
            sc[p] = MFMA(bs0, aH[p][ks], sc[p]);
            bi[p] = MFMA(bs1, aH[p][ks], bi[p]);
          }
        }
#pragma unroll
        for (int p = 0; p < 4; ++p) {
          f16x4 yv;
#pragma unroll
          for (int q = 0; q < 4; ++q) {
            float v = (sc[p][q] + scq[q]) * (float)zh[p][tt][q] + (bi[p][q] + biq[q]);
            v = fmaxf(v, 0.01f * v);
            yv[q] = (f16)v;
          }
          *(f16x4*)&sY[p * 16 + ln][c4] = yv;
        }
      }
      __syncthreads();
    } else {
      float o[4] = {0, 0, 0, 0};
#pragma unroll
      for (int tt = 0; tt < 4; ++tt) {
        const int c4 = ch * 64 + tt * 16 + g4;
        const float4 mv0 = *(const float4*)(mb3 + l * 256 + 2 * c4);
        const float4 mv1 = *(const float4*)(mb3 + l * 256 + 2 * c4 + 4);
        const float scq[4] = {mv0.x, mv0.z, mv1.x, mv1.z};
        const float biq[4] = {mv0.y, mv0.w, mv1.y, mv1.w};
        const float4 w5v = *(const float4*)(w5 + c4);
        const float w5q[4] = {w5v.x, w5v.y, w5v.z, w5v.w};
        f32x4 sc[4], bi[4];
#pragma unroll
        for (int p = 0; p < 4; ++p) {
          sc[p] = (f32x4){0.f,0.f,0.f,0.f};
          bi[p] = (f32x4){0.f,0.f,0.f,0.f};
        }
#pragma unroll
        for (int ks = 0; ks < 4; ++ks) {
          const f16x8 bs0 = ldB3<WS>(wsp3, mw3, l, ch, tt, 0, ks, lane);
          const f16x8 bs1 = ldB3<WS>(wsp3, mw3, l, ch, tt, 1, ks, lane);
#pragma unroll
          for (int p = 0; p < 4; ++p) {
            sc[p] = MFMA(bs0, aH[p][ks], sc[p]);
            bi[p] = MFMA(bs1, aH[p][ks], bi[p]);
          }
        }
#pragma unroll
        for (int p = 0; p < 4; ++p)
#pragma unroll
          for (int q = 0; q < 4; ++q) {
            float v = (sc[p][q] + scq[q]) * (float)zh[p][tt][q] + (bi[p][q] + biq[q]);
            v = fmaxf(v, 0.01f * v);
            o[p] += v * w5q[q];
          }
      }
#pragma unroll
      for (int p = 0; p < 4; ++p) {
        o[p] += __shfl_xor(o[p], 16, 64);
        o[p] += __shfl_xor(o[p], 32, 64);
      }
      if (lane < 16) {
#pragma unroll
        for (int p = 0; p < 4; ++p)
          sOut[p * 16 + ln][ch] = o[p];
      }
      __syncthreads();
      if (t < RPB) {
        float v = sOut[t][0] + sOut[t][1] + b5[0];
        v = fmaxf(v, 0.01f * v);
        out[r0 + t] = v;
      }
    }
  }
}

extern "C" void kernel_launch(void* const* d_in, const int* in_sizes, int n_in,
                              void* d_out, int out_size, void* d_ws, size_t ws_size,
                              hipStream_t stream) {
  const float* x    = (const float*)d_in[0];
  const float* meta = (const float*)d_in[1];
  const float* mw1  = (const float*)d_in[2];
  const float* mb1  = (const float*)d_in[3];
  const float* mw2  = (const float*)d_in[4];
  const float* mb2  = (const float*)d_in[5];
  const float* mw3  = (const float*)d_in[6];
  const float* mb3  = (const float*)d_in[7];
  const float* w1   = (const float*)d_in[8];
  const float* b1   = (const float*)d_in[9];
  const float* w2   = (const float*)d_in[10];
  const float* b2   = (const float*)d_in[11];
  const float* w3   = (const float*)d_in[12];
  const float* b3   = (const float*)d_in[13];
  const float* w4   = (const float*)d_in[14];
  const float* b4   = (const float*)d_in[15];
  const float* w5   = (const float*)d_in[16];
  const float* b5   = (const float*)d_in[17];
  float* out = (float*)d_out;

  const int nrows = in_sizes[0];        // 262144
  const int grid  = nrows / RPB;        // 4096

  const bool usews = (ws_size >= WS_BYTES) && (d_ws != nullptr);
  if (usews) {
    f16x8* wsp = (f16x8*)d_ws;
    hipLaunchKernelGGL(pack_weights, dim3((G_TOT + 255) / 256), dim3(256), 0, stream,
                       mw2, w2, w3, w4, mw3, wsp);
    hipLaunchKernelGGL(adain_mfma<true>, dim3(grid), dim3(NTHR), 0, stream,
                       x, meta, mw1, mb1, mw2, mb2, mw3, mb3,
                       w1, b1, w2, b2, w3, b3, w4, b4, w5, b5, wsp, out);
  } else {
    hipLaunchKernelGGL(adain_mfma<false>, dim3(grid), dim3(NTHR), 0, stream,
                       x, meta, mw1, mb1, mw2, mb2, mw3, mb3,
                       w1, b1, w2, b2, w3, b3, w4, b4, w5, b5, (const f16x8*)nullptr, out);
  }
}